// Round 6
// baseline (156.550 us; speedup 1.0000x reference)
//
#include <hip/hip_runtime.h>
#include <stdint.h>

#define TAGS 10
#define START_TAG 8
#define STOP_TAG 9
#define NEGV (-10000.0f)
#define SENT (-3.0e38f)

// DPP permute within 16-lane rows. ROW_ROR:r = 0x120+r, QUAD_PERM[1,0,3,2]=0xB1.
#define DPP_I(x, ctrl) __builtin_amdgcn_update_dpp(0, (x), (ctrl), 0xF, 0xF, true)

__device__ __forceinline__ float maxf3(float a, float b, float c) {
    return fmaxf(fmaxf(a, b), c);   // folds to v_max3_f32
}

// Fused Viterbi forward + backtrace. 16 lanes/seq (lane n = next-tag n),
// 4 seqs/wave. Forward: 16 DPP rotations gather prev fv; argmax carried in the
// low 4 mantissa bits of the score key, packed as (srcv^15) so ties resolve to
// the SMALLEST prev index (jnp.argmax semantics). Feats prefetched 16 steps
// ahead (3-buffer rotation). Backpointers: 2 nibbles/byte at bp[b][t] (8B/t),
// so the fused backtrace reads its own contiguous row with vector loads.
// __launch_bounds__(64, 1): only ~1 wave/SIMD of work exists (1024 waves on
// 1024 SIMDs), so let the register allocator use the full VGPR file instead of
// capping at 48 and spilling the inner loop to scratch (R5: 440 stall cyc/step).
__global__ __launch_bounds__(64, 1) void crf_fused_kernel(
    const float* __restrict__ feats,
    const int*   __restrict__ lengths,
    const float* __restrict__ trans,
    float*       __restrict__ out_scores,
    float*       __restrict__ out_path,
    uint8_t*     __restrict__ bp8,
    int B, int T)
{
    const int lane = threadIdx.x & 63;
    const int grp  = lane >> 4;
    const int n    = lane & 15;
    const int b4   = blockIdx.x * 4;
    const int b    = min(b4 + grp, B - 1);

    const int len = lengths[b];
    const int l0 = lengths[min(b4 + 0, B - 1)];
    const int l1 = lengths[min(b4 + 1, B - 1)];
    const int l2 = lengths[min(b4 + 2, B - 1)];
    const int l3 = lengths[min(b4 + 3, B - 1)];
    const int maxlen = max(max(l0, l1), max(l2, l3));
    const int len_eff = (n < TAGS) ? len : 0;   // dead lanes stay frozen

    // srcv[r] = source lane delivered by ROW_ROR:r (derived with the same DPP
    // op on the lane index — rotation-direction-proof).
    int srcv[16];
    srcv[0]  = n;
    srcv[1]  = DPP_I(n, 0x121);  srcv[2]  = DPP_I(n, 0x122);
    srcv[3]  = DPP_I(n, 0x123);  srcv[4]  = DPP_I(n, 0x124);
    srcv[5]  = DPP_I(n, 0x125);  srcv[6]  = DPP_I(n, 0x126);
    srcv[7]  = DPP_I(n, 0x127);  srcv[8]  = DPP_I(n, 0x128);
    srcv[9]  = DPP_I(n, 0x129);  srcv[10] = DPP_I(n, 0x12A);
    srcv[11] = DPP_I(n, 0x12B);  srcv[12] = DPP_I(n, 0x12C);
    srcv[13] = DPP_I(n, 0x12D);  srcv[14] = DPP_I(n, 0x12E);
    srcv[15] = DPP_I(n, 0x12F);

    // rotated transition row + tie-reversed index nibble
    float trowR[16];
    int   rsrc[16];
#pragma unroll
    for (int r = 0; r < 16; ++r) {
        const bool valid = (n < TAGS) && (srcv[r] < TAGS);
        const int  ti    = min(n, TAGS - 1) * TAGS + min(srcv[r], TAGS - 1);
        trowR[r] = valid ? trans[ti] : SENT;
        rsrc[r]  = srcv[r] ^ 15;         // max prefers LARGER key => smaller src
    }

    float fv = (n == START_TAG) ? 0.0f : NEGV;

    const int col = (n < TAGS) ? n : 0;
    const float* fb = feats + (size_t)b * T * TAGS + col;
    uint8_t* bpb = bp8 + (size_t)b * T * 8 + (n >> 1);     // [b][t] layout
    const bool store_lane = ((n & 1) == 0) && (n < TAGS);

#define LEAFK(r, ctrl) {                                                    \
        float rot_ = __int_as_float(DPP_I(__float_as_int(fv), ctrl));       \
        float lv_  = rot_ + trowR[r];                                       \
        k##r = __int_as_float((__float_as_int(lv_) & 0xFFFFFFF0) | rsrc[r]); }

    // one 8-step phase: issue loads 16 ahead into ld[], compute from use[]
    auto PHASE = [&](float (&use)[8], float (&ld)[8], int t0) {
#pragma unroll
        for (int i = 0; i < 8; ++i)
            ld[i] = fb[(size_t)min(t0 + 16 + i, T - 1) * TAGS];
#pragma unroll
        for (int i = 0; i < 8; ++i) {
            const int t = t0 + i;
            float k0, k1, k2, k3, k4, k5, k6, k7, k8, k9, k10, k11, k12, k13, k14, k15;
            {   float lv_ = fv + trowR[0];
                k0 = __int_as_float((__float_as_int(lv_) & 0xFFFFFFF0) | rsrc[0]); }
            LEAFK(1,  0x121); LEAFK(2,  0x122); LEAFK(3,  0x123);
            LEAFK(4,  0x124); LEAFK(5,  0x125); LEAFK(6,  0x126);
            LEAFK(7,  0x127); LEAFK(8,  0x128); LEAFK(9,  0x129);
            LEAFK(10, 0x12A); LEAFK(11, 0x12B); LEAFK(12, 0x12C);
            LEAFK(13, 0x12D); LEAFK(14, 0x12E); LEAFK(15, 0x12F);

            const float a = maxf3(k0, k1, k2);
            const float c = maxf3(k3, k4, k5);
            const float d = maxf3(k6, k7, k8);
            const float e = maxf3(k9, k10, k11);
            const float f = maxf3(k12, k13, k14);
            const float m = fmaxf(maxf3(a, c, d), maxf3(e, f, k15));

            const int idx = (__float_as_int(m) & 15) ^ 15;   // true prev tag
            const float fvn = m + use[i];                    // emission after max
            fv = (t < len_eff) ? fvn : fv;                   // freeze past length

            const int pidx = DPP_I(idx, 0xB1);               // partner lane^1
            if (t < T) {
                if (store_lane)
                    bpb[(size_t)t * 8] = (uint8_t)(idx | (pidx << 4));
            }
        }
    };

    float fA[8], fB[8], fC[8];
#pragma unroll
    for (int i = 0; i < 8; ++i) {
        fA[i] = fb[(size_t)min(i, T - 1) * TAGS];
        fB[i] = fb[(size_t)min(8 + i, T - 1) * TAGS];
    }
    for (int t0 = 0; t0 < maxlen; t0 += 24) {
        PHASE(fA, fC, t0);
        PHASE(fB, fA, t0 + 8);
        PHASE(fC, fB, t0 + 16);
    }
#undef LEAFK

    // terminal: key-packed all-reduce max within the 16-lane group
    const float ttr  = (n < TAGS) ? trans[STOP_TAG * TAGS + n] : SENT;
    const float term = fv + ttr;
    float kk = __int_as_float((__float_as_int(term) & 0xFFFFFFF0) | (n ^ 15));
    kk = fmaxf(kk, __int_as_float(DPP_I(__float_as_int(kk), 0x128)));
    kk = fmaxf(kk, __int_as_float(DPP_I(__float_as_int(kk), 0x124)));
    kk = fmaxf(kk, __int_as_float(DPP_I(__float_as_int(kk), 0x122)));
    kk = fmaxf(kk, __int_as_float(DPP_I(__float_as_int(kk), 0x121)));
    int tag = (__float_as_int(kk) & 15) ^ 15;

    if (n == 0)
        out_scores[b] = kk;

    // drain bp stores before re-reading them
    __builtin_amdgcn_s_waitcnt(0);
    __builtin_amdgcn_sched_barrier(0);

    // fused backtrace: lane n==0 of each group walks its own contiguous row
    if (n == 0) {
        const ulonglong2* bw2 = (const ulonglong2*)(bp8 + (size_t)b * T * 8);
        float* orow = out_path + (size_t)b * T;
        const int NB = (T + 15) / 16;
        const int P2 = T / 2;                // T is even (700)
        ulonglong2 wA[8], wB[8];

        auto loadblk = [&](int bi, ulonglong2* w) {
            if (bi < 0) return;
#pragma unroll
            for (int u = 0; u < 8; ++u)
                w[u] = bw2[min(bi * 8 + u, P2 - 1)];
        };
        auto compblk = [&](int bi, ulonglong2* w) {
            float buf[16];
#pragma unroll
            for (int u = 15; u >= 0; --u) {
                int t = bi * 16 + u;
                if (t < T) {
                    uint64_t word = (u & 1) ? w[u >> 1].y : w[u >> 1].x;
                    bool act = t < len;
                    buf[u] = act ? (float)tag : 0.0f;
                    if (act) tag = (int)((word >> (4 * tag)) & 15);
                }
            }
#pragma unroll
            for (int j = 0; j < 16; j += 4) {
                int t = bi * 16 + j;
                if (t + 3 < T)
                    *(float4*)(orow + t) = make_float4(buf[j], buf[j+1], buf[j+2], buf[j+3]);
            }
        };

        int bi = NB - 1;
        loadblk(bi, wA);
        loadblk(bi - 1, wB);
        for (; bi >= 0; bi -= 2) {
            compblk(bi, wA);
            loadblk(bi - 2, wA);
            if (bi - 1 >= 0) compblk(bi - 1, wB);
            loadblk(bi - 3, wB);
        }
    }
}

extern "C" void kernel_launch(void* const* d_in, const int* in_sizes, int n_in,
                              void* d_out, int out_size, void* d_ws, size_t ws_size,
                              hipStream_t stream)
{
    const float* feats   = (const float*)d_in[0];
    const int*   lengths = (const int*)d_in[1];
    const float* trans   = (const float*)d_in[2];
    const int B = in_sizes[1];
    const int T = in_sizes[0] / (B * TAGS);

    float* out_scores = (float*)d_out;       // [B]
    float* out_path   = (float*)d_out + B;   // [B, T] tags as floats

    uint8_t* bp8 = (uint8_t*)d_ws;           // [B][T] 8B words (5 bytes used)

    crf_fused_kernel<<<(B + 3) / 4, 64, 0, stream>>>(
        feats, lengths, trans, out_scores, out_path, bp8, B, T);
}